// Round 1
// baseline (49.512 us; speedup 1.0000x reference)
//
#include <hip/hip_runtime.h>

static constexpr int N_EP  = 8192;
static constexpr int T_LEN = 1024;
static constexpr float LMBDA = 0.95f;

// One wave (64 lanes) per episode row. Lane l owns timesteps [16l, 16l+16).
// Backward affine recurrence parallelized via per-lane fold + wave suffix-scan
// of affine maps (A,B), then per-lane replay with the true carry.
__global__ __launch_bounds__(256) void vtrace_kernel(
    const float* __restrict__ gammas,
    const float* __restrict__ vf_x,
    const float* __restrict__ rewards,
    const float* __restrict__ action_lls,
    const float* __restrict__ orig_lls,
    const int*   __restrict__ terminated,
    const int*   __restrict__ ep_len,
    float* __restrict__ adv_out,   // N*T
    float* __restrict__ vs_out)    // N*(T+1)
{
    const int n    = blockIdx.x * 4 + (threadIdx.x >> 6);
    const int lane = threadIdx.x & 63;
    if (n >= N_EP) return;
    const int t0 = lane << 4;

    const long rowT  = (long)n * T_LEN + t0;        // into stride-1024 arrays
    const long rowT1 = (long)n * (T_LEN + 1) + t0;  // into stride-1025 arrays

    float g[16], r[16], rho[16], vf[17];

    const float4* g4 = reinterpret_cast<const float4*>(gammas     + rowT);
    const float4* r4 = reinterpret_cast<const float4*>(rewards    + rowT);
    const float4* a4 = reinterpret_cast<const float4*>(action_lls + rowT);
    const float4* o4 = reinterpret_cast<const float4*>(orig_lls   + rowT);
#pragma unroll
    for (int q = 0; q < 4; ++q) {
        const float4 gg = g4[q];
        const float4 rr = r4[q];
        const float4 aa = a4[q];
        const float4 oo = o4[q];
        g[4*q+0] = gg.x; g[4*q+1] = gg.y; g[4*q+2] = gg.z; g[4*q+3] = gg.w;
        r[4*q+0] = rr.x; r[4*q+1] = rr.y; r[4*q+2] = rr.z; r[4*q+3] = rr.w;
        rho[4*q+0] = fminf(__expf(aa.x - oo.x), 1.0f);
        rho[4*q+1] = fminf(__expf(aa.y - oo.y), 1.0f);
        rho[4*q+2] = fminf(__expf(aa.z - oo.z), 1.0f);
        rho[4*q+3] = fminf(__expf(aa.w - oo.w), 1.0f);
    }
#pragma unroll
    for (int j = 0; j < 17; ++j) vf[j] = vf_x[rowT1 + j];

    // zero out discount at final step of terminated episodes
    const int kill = ep_len[n] - 1 - t0;
    if (terminated[n] != 0 && kill >= 0 && kill < 16) g[kill] = 0.0f;

    // Pass 1: fold this lane's 16 steps into affine map v_out = B + A * v_in
    // (v_in = v_diff entering from t0+16). gc = LMBDA*rho*g since C_MAX==RHO_MAX.
    float A = 1.0f, B = 0.0f;
#pragma unroll
    for (int j = 15; j >= 0; --j) {
        const float gc = LMBDA * rho[j] * g[j];
        const float dv = rho[j] * fmaf(g[j], vf[j + 1], r[j] - vf[j]);
        B = fmaf(gc, B, dv);
        A *= gc;
    }

    // Suffix scan (carry flows from high lanes to low): after step d, lane l
    // holds composition f_l∘...∘f_{min(l+2d-1,63)}.  h = f_self ∘ f_neighbor.
#pragma unroll
    for (int d = 1; d < 64; d <<= 1) {
        const float An = __shfl_down(A, d, 64);
        const float Bn = __shfl_down(B, d, 64);
        if (lane + d < 64) { B = fmaf(A, Bn, B); A *= An; }
    }
    float carry = __shfl_down(B, 1, 64);  // S_{l+1}(0) = v_diff[t0+16]
    if (lane == 63) carry = 0.0f;

    // Pass 2: replay with true carry, produce v_s and advantages.
    float v = carry;
    float vs_next = carry + vf[16];            // v_s[t0+16]
    if (lane == 63) vs_out[rowT1 + 16] = vs_next;  // v_s[:, T] = vf_x[:, T]

    float vs_arr[16], adv_arr[16];
#pragma unroll
    for (int j = 15; j >= 0; --j) {
        const float gc = LMBDA * rho[j] * g[j];
        const float dv = rho[j] * fmaf(g[j], vf[j + 1], r[j] - vf[j]);
        v = fmaf(gc, v, dv);                   // v_diff[t0+j]
        const float vsj = v + vf[j];           // v_s[t0+j]
        adv_arr[j] = rho[j] * fmaf(r[j] * g[j], vs_next, -vf[j]);
        vs_arr[j]  = vsj;
        vs_next = vsj;
    }

    float4* adv4 = reinterpret_cast<float4*>(adv_out + rowT);
#pragma unroll
    for (int q = 0; q < 4; ++q)
        adv4[q] = make_float4(adv_arr[4*q+0], adv_arr[4*q+1],
                              adv_arr[4*q+2], adv_arr[4*q+3]);
#pragma unroll
    for (int j = 0; j < 16; ++j) vs_out[rowT1 + j] = vs_arr[j];
}

extern "C" void kernel_launch(void* const* d_in, const int* in_sizes, int n_in,
                              void* d_out, int out_size, void* d_ws, size_t ws_size,
                              hipStream_t stream) {
    const float* gammas     = (const float*)d_in[0];
    const float* vf_x       = (const float*)d_in[1];
    const float* rewards    = (const float*)d_in[2];
    const float* action_lls = (const float*)d_in[3];
    const float* orig_lls   = (const float*)d_in[4];
    const int*   terminated = (const int*)d_in[5];
    const int*   ep_len     = (const int*)d_in[6];

    float* adv = (float*)d_out;
    float* vs  = adv + (long)N_EP * T_LEN;

    dim3 grid(N_EP / 4), block(256);
    hipLaunchKernelGGL(vtrace_kernel, grid, block, 0, stream,
                       gammas, vf_x, rewards, action_lls, orig_lls,
                       terminated, ep_len, adv, vs);
}

// Round 2
// 40.416 us; speedup vs baseline: 1.2251x; 1.2251x over previous
//
#include <hip/hip_runtime.h>

static constexpr int N_EP  = 8192;
static constexpr int T_LEN = 1024;
static constexpr float LMBDA = 0.95f;

// One wave per episode row. Cyclic-chunk ownership: in round q (q=3..0, backward),
// lane l owns timesteps t = q*256 + l*4 + {0..3}. All global accesses are
// lane-stride-4B (or 16B) coalesced, including the odd-stride vf_x/vs rows.
// Backward affine recurrence: per-lane 4-step fold -> wave suffix-scan of
// (A,B) affine maps (6 shfl steps) -> replay with true carry. Rounds are
// chained by broadcasting lane 0's final v (v_diff at the round boundary).
__global__ __launch_bounds__(256) void vtrace_kernel(
    const float* __restrict__ gammas,
    const float* __restrict__ vf_x,
    const float* __restrict__ rewards,
    const float* __restrict__ action_lls,
    const float* __restrict__ orig_lls,
    const int*   __restrict__ terminated,
    const int*   __restrict__ ep_len,
    float* __restrict__ adv_out,   // N*T
    float* __restrict__ vs_out)    // N*(T+1)
{
    const int n    = blockIdx.x * 4 + (threadIdx.x >> 6);
    const int lane = threadIdx.x & 63;
    if (n >= N_EP) return;

    const long rowT  = (long)n * T_LEN;
    const long rowT1 = (long)n * (T_LEN + 1);
    const int  term  = terminated[n];
    const int  kill  = ep_len[n] - 1;   // global timestep whose gamma is zeroed

    float v_in = 0.0f;                  // v_diff entering from t = (q+1)*256

#pragma unroll
    for (int q = 3; q >= 0; --q) {
        const int base = q * 256 + lane * 4;

        // ---- loads (all coalesced; float4 arrays are 16B aligned) ----
        const float4 gg = *reinterpret_cast<const float4*>(gammas     + rowT + base);
        const float4 rr = *reinterpret_cast<const float4*>(rewards    + rowT + base);
        const float4 aa = *reinterpret_cast<const float4*>(action_lls + rowT + base);
        const float4 oo = *reinterpret_cast<const float4*>(orig_lls   + rowT + base);
        float g[4] = {gg.x, gg.y, gg.z, gg.w};
        float r[4] = {rr.x, rr.y, rr.z, rr.w};
        float rho[4];
        rho[0] = fminf(__expf(aa.x - oo.x), 1.0f);
        rho[1] = fminf(__expf(aa.y - oo.y), 1.0f);
        rho[2] = fminf(__expf(aa.z - oo.z), 1.0f);
        rho[3] = fminf(__expf(aa.w - oo.w), 1.0f);

        float vf[5];                    // vf_x row has stride 1025 (no 16B align)
#pragma unroll
        for (int k = 0; k < 5; ++k) vf[k] = vf_x[rowT1 + base + k];

        // zero gamma at final step of terminated episodes (compile-time indices)
        if (term) {
#pragma unroll
            for (int j = 0; j < 4; ++j)
                if (kill == base + j) g[j] = 0.0f;
        }

        // ---- fold 4 steps into affine map: v[base] = B + A * v[base+4] ----
        float A = 1.0f, B = 0.0f;
#pragma unroll
        for (int j = 3; j >= 0; --j) {
            const float gc = LMBDA * rho[j] * g[j];
            const float dv = rho[j] * fmaf(g[j], vf[j + 1], r[j] - vf[j]);
            B = fmaf(gc, B, dv);
            A *= gc;
        }

        // ---- wave suffix-scan: lane l composes maps of lanes l..63 ----
#pragma unroll
        for (int d = 1; d < 64; d <<= 1) {
            const float An = __shfl_down(A, d, 64);
            const float Bn = __shfl_down(B, d, 64);
            if (lane + d < 64) { B = fmaf(A, Bn, B); A *= An; }
        }
        const float A1 = __shfl_down(A, 1, 64);
        const float B1 = __shfl_down(B, 1, 64);
        const float carry = (lane == 63) ? v_in : fmaf(A1, v_in, B1); // v_diff[base+4]

        float vs_next = carry + vf[4];              // v_s[base+4]
        if (q == 3 && lane == 63)
            vs_out[rowT1 + T_LEN] = vs_next;        // v_s[:, T] = vf_x[:, T]

        // ---- replay with true carry ----
        float v = carry;
        float vsa[4], adv[4];
#pragma unroll
        for (int j = 3; j >= 0; --j) {
            const float gc = LMBDA * rho[j] * g[j];
            const float dv = rho[j] * fmaf(g[j], vf[j + 1], r[j] - vf[j]);
            v = fmaf(gc, v, dv);                    // v_diff[base+j]
            vsa[j] = v + vf[j];                     // v_s[base+j]
            adv[j] = rho[j] * fmaf(r[j] * g[j], vs_next, -vf[j]);
            vs_next = vsa[j];
        }

        // ---- stores (coalesced) ----
        *reinterpret_cast<float4*>(adv_out + rowT + base) =
            make_float4(adv[0], adv[1], adv[2], adv[3]);
#pragma unroll
        for (int j = 0; j < 4; ++j) vs_out[rowT1 + base + j] = vsa[j];

        // carry for next (lower-t) round: lane 0 holds v_diff[q*256]
        v_in = __shfl(v, 0, 64);
    }
}

extern "C" void kernel_launch(void* const* d_in, const int* in_sizes, int n_in,
                              void* d_out, int out_size, void* d_ws, size_t ws_size,
                              hipStream_t stream) {
    const float* gammas     = (const float*)d_in[0];
    const float* vf_x       = (const float*)d_in[1];
    const float* rewards    = (const float*)d_in[2];
    const float* action_lls = (const float*)d_in[3];
    const float* orig_lls   = (const float*)d_in[4];
    const int*   terminated = (const int*)d_in[5];
    const int*   ep_len     = (const int*)d_in[6];

    float* adv = (float*)d_out;
    float* vs  = adv + (long)N_EP * T_LEN;

    dim3 grid(N_EP / 4), block(256);
    hipLaunchKernelGGL(vtrace_kernel, grid, block, 0, stream,
                       gammas, vf_x, rewards, action_lls, orig_lls,
                       terminated, ep_len, adv, vs);
}